// Round 5
// baseline (154.293 us; speedup 1.0000x reference)
//
#include <hip/hip_runtime.h>
#include <stdint.h>

#define N_G   1024
#define H_IMG 128
#define W_IMG 128
#define TILE  8
#define TILES_X (W_IMG / TILE)            // 16
#define N_TILES (TILES_X * (H_IMG/TILE))  // 256
#define FXc   128.0f
#define FYc   128.0f

// ws layout (float offsets):
//   payload[1024*12]  (48B records: gx,gy,A,B | C,op,r,g | b,rc2,0,0)
//   sorted_payload[1024*12]
//   keys u64[1024]            (2048 floats)
//   flags uint[2*256]         (two single-use grid barriers)
#define WS_PAY    0
#define WS_SORTED (N_G*12)
#define WS_KEYS   (N_G*24)
#define WS_FLAGS  (N_G*26)

// Single-use grid barrier. ws is poisoned to 0xAA before every launch, so
// flags start at 0xAAAAAAAA != 1 — no init dispatch needed. 256 blocks x 64
// threads with __launch_bounds__(64,1) are co-resident on 256 CUs, so the
// spin cannot deadlock. __threadfence() = agent-scope fence (L2 wb/inv)
// handles cross-XCD visibility of payload/keys/sorted written by other blocks.
__device__ __forceinline__ void grid_barrier(unsigned int* flags, int lane) {
    __syncthreads();
    __threadfence();
    if (lane == 0)
        __hip_atomic_store(flags + blockIdx.x, 1u,
                           __ATOMIC_RELEASE, __HIP_MEMORY_SCOPE_AGENT);
    for (;;) {
        bool ok = true;
        #pragma unroll
        for (int i = 0; i < 4; ++i) {
            unsigned v = __hip_atomic_load(flags + lane * 4 + i,
                                           __ATOMIC_ACQUIRE, __HIP_MEMORY_SCOPE_AGENT);
            ok &= (v == 1u);
        }
        if (__ballot(ok) == 0xFFFFFFFFFFFFFFFFull) break;
    }
    __threadfence();
    __syncthreads();
}

__global__ __launch_bounds__(64, 1) void gauss_fused_kernel(
    const float* __restrict__ means3D, const float* __restrict__ opac,
    const float* __restrict__ shs,     const float* __restrict__ scales,
    const float* __restrict__ rot,     const float* __restrict__ vm,
    const float* __restrict__ pm,      const float* __restrict__ campos,
    const float* __restrict__ bg,
    float* __restrict__ out,           // color (3,H,W) then radii (N_G)
    float4* __restrict__ payload, float4* __restrict__ sorted_pay,
    unsigned long long* __restrict__ keys, unsigned int* __restrict__ flags)
{
    __shared__ unsigned long long k_lds[N_G];   // 8 KB; reused as batch in stage C
    const int lane = threadIdx.x;
    const int bid  = blockIdx.x;

    // ================= Stage A: preprocess (blocks 0-15, gaussian = bid*64+lane) =================
    if (bid < N_G / 64) {
        const int n = bid * 64 + lane;

        float mx = means3D[n*3+0], my = means3D[n*3+1], mz = means3D[n*3+2];

        float pv0   = mx*vm[0] + my*vm[4] + mz*vm[8]  + vm[12];
        float pv1   = mx*vm[1] + my*vm[5] + mz*vm[9]  + vm[13];
        float depth = mx*vm[2] + my*vm[6] + mz*vm[10] + vm[14];
        bool dvalid = depth > 0.2f;

        float ph0 = mx*pm[0] + my*pm[4] + mz*pm[8]  + pm[12];
        float ph1 = mx*pm[1] + my*pm[5] + mz*pm[9]  + pm[13];
        float ph3 = mx*pm[3] + my*pm[7] + mz*pm[11] + pm[15];
        float invw = 1.0f / (ph3 + 1e-7f);
        float pp0 = ph0 * invw, pp1 = ph1 * invw;

        float4 q = *(const float4*)(rot + n*4);
        float qn = sqrtf(q.x*q.x + q.y*q.y + q.z*q.z + q.w*q.w);
        float qr = q.x/qn, qx = q.y/qn, qy = q.z/qn, qz = q.w/qn;
        float R00 = 1.f - 2.f*(qy*qy + qz*qz), R01 = 2.f*(qx*qy - qr*qz), R02 = 2.f*(qx*qz + qr*qy);
        float R10 = 2.f*(qx*qy + qr*qz), R11 = 1.f - 2.f*(qx*qx + qz*qz), R12 = 2.f*(qy*qz - qr*qx);
        float R20 = 2.f*(qx*qz - qr*qy), R21 = 2.f*(qy*qz + qr*qx), R22 = 1.f - 2.f*(qx*qx + qy*qy);

        float s0 = scales[n*3+0], s1 = scales[n*3+1], s2 = scales[n*3+2];
        float M00=R00*s0, M01=R01*s1, M02=R02*s2;
        float M10=R10*s0, M11=R11*s1, M12=R12*s2;
        float M20=R20*s0, M21=R21*s1, M22=R22*s2;

        float S00 = M00*M00 + M01*M01 + M02*M02;
        float S01 = M00*M10 + M01*M11 + M02*M12;
        float S02 = M00*M20 + M01*M21 + M02*M22;
        float S11 = M10*M10 + M11*M11 + M12*M12;
        float S12 = M10*M20 + M11*M21 + M12*M22;
        float S22 = M20*M20 + M21*M21 + M22*M22;

        float tz   = dvalid ? depth : 1.0f;
        float txtz = fminf(fmaxf(pv0 / tz, -0.65f), 0.65f) * tz;
        float tytz = fminf(fmaxf(pv1 / tz, -0.65f), 0.65f) * tz;
        float J00 = FXc / tz, J02 = -FXc * txtz / (tz*tz);
        float J11 = FYc / tz, J12 = -FYc * tytz / (tz*tz);

        float T20k0 = J00*vm[0] + J02*vm[2];
        float T20k1 = J00*vm[4] + J02*vm[6];
        float T20k2 = J00*vm[8] + J02*vm[10];
        float T21k0 = J11*vm[1] + J12*vm[2];
        float T21k1 = J11*vm[5] + J12*vm[6];
        float T21k2 = J11*vm[9] + J12*vm[10];

        float U00 = T20k0*S00 + T20k1*S01 + T20k2*S02;
        float U01 = T20k0*S01 + T20k1*S11 + T20k2*S12;
        float U02 = T20k0*S02 + T20k1*S12 + T20k2*S22;
        float U10 = T21k0*S00 + T21k1*S01 + T21k2*S02;
        float U11 = T21k0*S01 + T21k1*S11 + T21k2*S12;
        float U12 = T21k0*S02 + T21k1*S12 + T21k2*S22;
        float cov00 = U00*T20k0 + U01*T20k1 + U02*T20k2;
        float cov01 = U00*T21k0 + U01*T21k1 + U02*T21k2;
        float cov11 = U10*T21k0 + U11*T21k1 + U12*T21k2;

        float a = cov00 + 0.3f, b = cov01, c = cov11 + 0.3f;
        float det = a*c - b*b;
        bool valid = dvalid && (det > 0.0f);
        float inv_det = (det > 0.0f) ? (1.0f / det) : 1.0f;
        float conA = c * inv_det, conB = -b * inv_det, conC = a * inv_det;

        float mid  = 0.5f * (a + c);
        float lam1 = mid + sqrtf(fmaxf(0.1f, mid*mid - det));
        out[3*H_IMG*W_IMG + n] = valid ? ceilf(3.0f * sqrtf(lam1)) : 0.0f;  // radii

        float gx = ((pp0 + 1.0f) * (float)W_IMG - 1.0f) * 0.5f;
        float gy = ((pp1 + 1.0f) * (float)H_IMG - 1.0f) * 0.5f;

        float dxm = mx - campos[0], dym = my - campos[1], dzm = mz - campos[2];
        float dn = sqrtf(dxm*dxm + dym*dym + dzm*dzm);
        float sx = dxm/dn, sy = dym/dn, sz = dzm/dn;
        float xx = sx*sx, yy = sy*sy, zz = sz*sz;
        float xy = sx*sy, yz = sy*sz, xz = sx*sz;
        const float4* sh4 = (const float4*)(shs + n*48);
        float shf[48];
        #pragma unroll
        for (int k = 0; k < 12; ++k) {
            float4 v = sh4[k];
            shf[k*4+0]=v.x; shf[k*4+1]=v.y; shf[k*4+2]=v.z; shf[k*4+3]=v.w;
        }
        float col[3];
        #pragma unroll
        for (int ch = 0; ch < 3; ++ch) {
            float res = 0.28209479177387814f * shf[0*3+ch]
                - 0.4886025119029199f * sy * shf[1*3+ch]
                + 0.4886025119029199f * sz * shf[2*3+ch]
                - 0.4886025119029199f * sx * shf[3*3+ch]
                + 1.0925484305920792f  * xy * shf[4*3+ch]
                + (-1.0925484305920792f) * yz * shf[5*3+ch]
                + 0.31539156525252005f * (2.f*zz - xx - yy) * shf[6*3+ch]
                + (-1.0925484305920792f) * xz * shf[7*3+ch]
                + 0.5462742152960396f  * (xx - yy) * shf[8*3+ch]
                + (-0.5900435899266435f) * sy * (3.f*xx - yy) * shf[9*3+ch]
                + 2.890611442640554f   * xy * sz * shf[10*3+ch]
                + (-0.4570457994644658f) * sy * (4.f*zz - xx - yy) * shf[11*3+ch]
                + 0.3731763325901154f  * sz * (2.f*zz - 3.f*xx - 3.f*yy) * shf[12*3+ch]
                + (-0.4570457994644658f) * sx * (4.f*zz - xx - yy) * shf[13*3+ch]
                + 1.445305721320277f   * sz * (xx - yy) * shf[14*3+ch]
                + (-0.5900435899266435f) * sx * (xx - 3.f*yy) * shf[15*3+ch];
            col[ch] = fmaxf(res + 0.5f, 0.0f);
        }

        float op = opac[n];
        float op255 = op * 255.0f;
        float rc2 = (valid && op255 > 1.0f) ? (2.0f * logf(op255) * lam1 * 1.01f + 1.0f)
                                            : -1.0f;

        payload[n*3+0] = make_float4(gx, gy, conA, conB);
        payload[n*3+1] = make_float4(conC, op, col[0], col[1]);
        payload[n*3+2] = make_float4(col[2], rc2, 0.f, 0.f);

        unsigned int kb = valid ? __float_as_uint(depth) : 0x7F800000u;
        keys[n] = ((unsigned long long)kb << 32) | (unsigned int)n;
    }

    // ================= Barrier 1 =================
    grid_barrier(flags, lane);

    // ================= Stage B: rank sort + scatter (blocks 0-15) =================
    if (bid < N_G / 64) {
        #pragma unroll
        for (int i = 0; i < N_G / 64; ++i)
            k_lds[lane + i * 64] = keys[lane + i * 64];
        __syncthreads();

        const int n = bid * 64 + lane;
        unsigned long long mine = k_lds[n];
        int rank = 0;
        #pragma unroll 16
        for (int j = 0; j < N_G; ++j)
            rank += (k_lds[j] < mine) ? 1 : 0;   // keys unique (idx in low bits)

        float4 p0 = payload[n*3+0], p1 = payload[n*3+1], p2 = payload[n*3+2];
        sorted_pay[rank*3+0] = p0;
        sorted_pay[rank*3+1] = p1;
        sorted_pay[rank*3+2] = p2;
    }

    // ================= Barrier 2 =================
    grid_barrier(flags + N_TILES, lane);

    // ================= Stage C: per-tile streaming cull + blend =================
    float* batch = (float*)k_lds;                 // reuse LDS: 64*16*4B = 4 KB
    const int tx = bid & (TILES_X - 1), ty = bid / TILES_X;
    const float x0 = (float)(tx * TILE), x1 = x0 + (float)(TILE - 1);
    const float y0 = (float)(ty * TILE), y1 = y0 + (float)(TILE - 1);
    const float px = x0 + (float)(lane & (TILE - 1));
    const float py = y0 + (float)(lane / TILE);

    float T = 1.0f, Tfin = 1.0f, cr = 0.f, cg = 0.f, cb = 0.f;
    bool live = true;

    const float4* pay = sorted_pay;
    float4 a0 = pay[lane*3+0], a1 = pay[lane*3+1], a2 = pay[lane*3+2];

    for (int base = 0; base < N_G; base += 64) {
        float4 n0, n1, n2;
        if (base + 64 < N_G) {
            const float4* np = pay + (base + 64 + lane) * 3;
            n0 = np[0]; n1 = np[1]; n2 = np[2];
        }

        // cull from registers (rc2 in a2.y; invalid records carry rc2 = -1)
        float cx = fminf(fmaxf(a0.x, x0), x1) - a0.x;
        float cy = fminf(fmaxf(a0.y, y0), y1) - a0.y;
        bool pass = (cx*cx + cy*cy) <= a2.y;
        unsigned long long mask = __ballot(pass);

        if (mask != 0ull) {
            int pos = __popcll(mask & ((1ull << lane) - 1ull));
            if (pass) {
                float4* bp = (float4*)(batch + pos * 16);
                bp[0] = a0; bp[1] = a1; bp[2] = a2;
            }
            __syncthreads();
            int nb = __popcll(mask);
            for (int j = 0; j < nb; ++j) {
                float4 g0 = *(const float4*)(batch + j * 16);      // gx gy A B
                float4 g1 = *(const float4*)(batch + j * 16 + 4);  // C op r g
                float  b2 = batch[j * 16 + 8];                     // b
                float dx = g0.x - px, dy = g0.y - py;
                float power = -0.5f * (g0.z*dx*dx + g1.x*dy*dy) - g0.w*dx*dy;
                float alpha = fminf(0.99f, g1.y * __expf(power));
                if (live && power <= 0.0f && alpha >= (1.0f/255.0f)) {
                    float Tnew = T * (1.0f - alpha);
                    if (Tnew < 1e-4f) {
                        live = false;          // exact: ae_i and all later ae are 0
                    } else {
                        float w = T * alpha;
                        cr += w * g1.z; cg += w * g1.w; cb += w * b2;
                        Tfin *= (1.0f - alpha);
                        T = Tnew;
                    }
                }
            }
            __syncthreads();
            if (__ballot(live) == 0ull) break;
        }

        a0 = n0; a1 = n1; a2 = n2;
    }

    int p = (int)py * W_IMG + (int)px;
    out[p]                 = cr + bg[0] * Tfin;
    out[H_IMG*W_IMG + p]   = cg + bg[1] * Tfin;
    out[2*H_IMG*W_IMG + p] = cb + bg[2] * Tfin;
}

extern "C" void kernel_launch(void* const* d_in, const int* in_sizes, int n_in,
                              void* d_out, int out_size, void* d_ws, size_t ws_size,
                              hipStream_t stream) {
    const float* means3D = (const float*)d_in[0];
    const float* opac    = (const float*)d_in[2];
    const float* shs     = (const float*)d_in[3];
    const float* scales  = (const float*)d_in[4];
    const float* rot     = (const float*)d_in[5];
    const float* vm      = (const float*)d_in[6];
    const float* pm      = (const float*)d_in[7];
    const float* campos  = (const float*)d_in[8];
    const float* bg      = (const float*)d_in[9];

    float* out = (float*)d_out;
    float* wsf = (float*)d_ws;
    float4*             payload = (float4*)(wsf + WS_PAY);
    float4*             sorted  = (float4*)(wsf + WS_SORTED);
    unsigned long long* keys    = (unsigned long long*)(wsf + WS_KEYS);
    unsigned int*       flags   = (unsigned int*)(wsf + WS_FLAGS);

    gauss_fused_kernel<<<N_TILES, 64, 0, stream>>>(
        means3D, opac, shs, scales, rot, vm, pm, campos, bg,
        out, payload, sorted, keys, flags);
}

// Round 6
// 105.325 us; speedup vs baseline: 1.4649x; 1.4649x over previous
//
#include <hip/hip_runtime.h>
#include <stdint.h>

#define N_G   1024
#define H_IMG 128
#define W_IMG 128
#define TILE  8
#define TILES_X (W_IMG / TILE)            // 16
#define N_TILES (TILES_X * (H_IMG/TILE))  // 256
#define FXc   128.0f
#define FYc   128.0f

// One dispatch, zero inter-block communication. Each block owns one 8x8 tile
// and redundantly recomputes all per-gaussian data it needs (cheaper than any
// cross-block handoff: grid-barrier spin measured ~40us/barrier in R5, extra
// dispatch ~13us in R3/R4, redundant prep ~2-3us).
__global__ __launch_bounds__(64) void gauss_tile_kernel(
    const float* __restrict__ means3D, const float* __restrict__ opac,
    const float* __restrict__ shs,     const float* __restrict__ scales,
    const float* __restrict__ rot,     const float* __restrict__ vm,
    const float* __restrict__ pm,      const float* __restrict__ campos,
    const float* __restrict__ bg,
    float* __restrict__ out)           // color (3,H,W) then radii (N_G)
{
    // SoA conic data for all gaussians (stride-1 => bank-conflict-free)
    __shared__ float gxA[N_G], gyA[N_G], cAA[N_G], cBA[N_G], cCA[N_G], opA[N_G];
    __shared__ unsigned long long keys[N_G];   // culled survivors, then sorted
    __shared__ float colR[64], colG[64], colB[64];

    const int lane = threadIdx.x;
    const int bid  = blockIdx.x;
    const int tx = bid & (TILES_X - 1), ty = bid / TILES_X;
    const float x0 = (float)(tx * TILE), x1 = x0 + (float)(TILE - 1);
    const float y0 = (float)(ty * TILE), y1 = y0 + (float)(TILE - 1);
    const float px = x0 + (float)(lane & (TILE - 1));
    const float py = y0 + (float)(lane / TILE);

    // per-lane register stash of cull info for the 16 gaussians this lane preps
    float rgx[16], rgy[16], rrc[16];
    unsigned int rdp[16];

    // ---------------- Phase 1: conic prep for ALL gaussians ----------------
    for (int k = 0; k < N_G / 64; ++k) {
        const int n = k * 64 + lane;

        float mx = means3D[n*3+0], my = means3D[n*3+1], mz = means3D[n*3+2];

        float pv0   = mx*vm[0] + my*vm[4] + mz*vm[8]  + vm[12];
        float pv1   = mx*vm[1] + my*vm[5] + mz*vm[9]  + vm[13];
        float depth = mx*vm[2] + my*vm[6] + mz*vm[10] + vm[14];
        bool dvalid = depth > 0.2f;

        float ph0 = mx*pm[0] + my*pm[4] + mz*pm[8]  + pm[12];
        float ph1 = mx*pm[1] + my*pm[5] + mz*pm[9]  + pm[13];
        float ph3 = mx*pm[3] + my*pm[7] + mz*pm[11] + pm[15];
        float invw = 1.0f / (ph3 + 1e-7f);
        float pp0 = ph0 * invw, pp1 = ph1 * invw;

        float4 q = *(const float4*)(rot + n*4);
        float qn = sqrtf(q.x*q.x + q.y*q.y + q.z*q.z + q.w*q.w);
        float qr = q.x/qn, qx = q.y/qn, qy = q.z/qn, qz = q.w/qn;
        float R00 = 1.f - 2.f*(qy*qy + qz*qz), R01 = 2.f*(qx*qy - qr*qz), R02 = 2.f*(qx*qz + qr*qy);
        float R10 = 2.f*(qx*qy + qr*qz), R11 = 1.f - 2.f*(qx*qx + qz*qz), R12 = 2.f*(qy*qz - qr*qx);
        float R20 = 2.f*(qx*qz - qr*qy), R21 = 2.f*(qy*qz + qr*qx), R22 = 1.f - 2.f*(qx*qx + qy*qy);

        float s0 = scales[n*3+0], s1 = scales[n*3+1], s2 = scales[n*3+2];
        float M00=R00*s0, M01=R01*s1, M02=R02*s2;
        float M10=R10*s0, M11=R11*s1, M12=R12*s2;
        float M20=R20*s0, M21=R21*s1, M22=R22*s2;

        float S00 = M00*M00 + M01*M01 + M02*M02;
        float S01 = M00*M10 + M01*M11 + M02*M12;
        float S02 = M00*M20 + M01*M21 + M02*M22;
        float S11 = M10*M10 + M11*M11 + M12*M12;
        float S12 = M10*M20 + M11*M21 + M12*M22;
        float S22 = M20*M20 + M21*M21 + M22*M22;

        float tz   = dvalid ? depth : 1.0f;
        float txtz = fminf(fmaxf(pv0 / tz, -0.65f), 0.65f) * tz;
        float tytz = fminf(fmaxf(pv1 / tz, -0.65f), 0.65f) * tz;
        float J00 = FXc / tz, J02 = -FXc * txtz / (tz*tz);
        float J11 = FYc / tz, J12 = -FYc * tytz / (tz*tz);

        float T20k0 = J00*vm[0] + J02*vm[2];
        float T20k1 = J00*vm[4] + J02*vm[6];
        float T20k2 = J00*vm[8] + J02*vm[10];
        float T21k0 = J11*vm[1] + J12*vm[2];
        float T21k1 = J11*vm[5] + J12*vm[6];
        float T21k2 = J11*vm[9] + J12*vm[10];

        float U00 = T20k0*S00 + T20k1*S01 + T20k2*S02;
        float U01 = T20k0*S01 + T20k1*S11 + T20k2*S12;
        float U02 = T20k0*S02 + T20k1*S12 + T20k2*S22;
        float U10 = T21k0*S00 + T21k1*S01 + T21k2*S02;
        float U11 = T21k0*S01 + T21k1*S11 + T21k2*S12;
        float U12 = T21k0*S02 + T21k1*S12 + T21k2*S22;
        float cov00 = U00*T20k0 + U01*T20k1 + U02*T20k2;
        float cov01 = U00*T21k0 + U01*T21k1 + U02*T21k2;
        float cov11 = U10*T21k0 + U11*T21k1 + U12*T21k2;

        float a = cov00 + 0.3f, b = cov01, c = cov11 + 0.3f;
        float det = a*c - b*b;
        bool valid = dvalid && (det > 0.0f);
        float inv_det = (det > 0.0f) ? (1.0f / det) : 1.0f;
        float conA = c * inv_det, conB = -b * inv_det, conC = a * inv_det;

        float mid  = 0.5f * (a + c);
        float lam1 = mid + sqrtf(fmaxf(0.1f, mid*mid - det));
        if (bid == 0)
            out[3*H_IMG*W_IMG + n] = valid ? ceilf(3.0f * sqrtf(lam1)) : 0.0f;

        float gx = ((pp0 + 1.0f) * (float)W_IMG - 1.0f) * 0.5f;
        float gy = ((pp1 + 1.0f) * (float)H_IMG - 1.0f) * 0.5f;

        float op = opac[n];
        // conservative cull radius^2: alpha >= 1/255 needs |d|^2 <= 2 ln(255 op) lam1
        float op255 = op * 255.0f;
        float rc2 = (valid && op255 > 1.0f) ? (2.0f * logf(op255) * lam1 * 1.01f + 1.0f)
                                            : -1.0f;

        gxA[n] = gx; gyA[n] = gy; cAA[n] = conA; cBA[n] = conB;
        cCA[n] = conC; opA[n] = op;
        rgx[k] = gx; rgy[k] = gy; rrc[k] = rc2;
        rdp[k] = __float_as_uint(depth);   // depth>0.2 for valid => bit order = value order
    }
    __syncthreads();

    // ---------------- Phase 2: cull + ballot compaction ----------------
    int cnt = 0;                            // wave-uniform
    for (int k = 0; k < N_G / 64; ++k) {
        float cx = fminf(fmaxf(rgx[k], x0), x1) - rgx[k];
        float cy = fminf(fmaxf(rgy[k], y0), y1) - rgy[k];
        bool pass = (cx*cx + cy*cy) <= rrc[k];   // invalid carry rc2=-1 -> fail
        unsigned long long mask = __ballot(pass);
        if (pass) {
            int pos = cnt + __popcll(mask & ((1ull << lane) - 1ull));
            keys[pos] = ((unsigned long long)rdp[k] << 32) | (unsigned int)(k*64 + lane);
        }
        cnt += (int)__popcll(mask);
    }
    const int M = cnt;
    __syncthreads();

    // ---------------- Phase 3: bitonic sort survivors by (depth, idx) ----------------
    // Canonical total order (keys unique) == reference stable depth argsort
    // restricted to this tile's survivors — exact.
    int P = 1; while (P < M) P <<= 1;
    for (int i = M + lane; i < P; i += 64) keys[i] = ~0ull;
    __syncthreads();
    for (int k = 2; k <= P; k <<= 1) {
        for (int j = k >> 1; j > 0; j >>= 1) {
            for (int i = lane; i < P; i += 64) {
                int l = i ^ j;
                if (l > i) {
                    unsigned long long ka = keys[i], kb = keys[l];
                    bool asc = ((i & k) == 0);
                    if ((ka > kb) == asc) { keys[i] = kb; keys[l] = ka; }
                }
            }
            __syncthreads();
        }
    }

    // ---------------- Phase 4: blend, lazy SH color per 64-batch ----------------
    const float cpx = campos[0], cpy = campos[1], cpz = campos[2];
    float T = 1.0f, Tfin = 1.0f, cr = 0.f, cg = 0.f, cb = 0.f;
    bool live = true;

    for (int base = 0; base < M; base += 64) {
        int j2 = base + lane;
        if (j2 < M) {
            int idx = (int)(keys[j2] & 0xFFFFFFFFu);
            float mx = means3D[idx*3+0], my = means3D[idx*3+1], mz = means3D[idx*3+2];
            float dxm = mx - cpx, dym = my - cpy, dzm = mz - cpz;
            float dn = sqrtf(dxm*dxm + dym*dym + dzm*dzm);
            float sx = dxm/dn, sy = dym/dn, sz = dzm/dn;
            float xx = sx*sx, yy = sy*sy, zz = sz*sz;
            float xy = sx*sy, yz = sy*sz, xz = sx*sz;
            const float4* sh4 = (const float4*)(shs + idx*48);
            float shf[48];
            #pragma unroll
            for (int t = 0; t < 12; ++t) {
                float4 v = sh4[t];
                shf[t*4+0]=v.x; shf[t*4+1]=v.y; shf[t*4+2]=v.z; shf[t*4+3]=v.w;
            }
            float col[3];
            #pragma unroll
            for (int ch = 0; ch < 3; ++ch) {
                float res = 0.28209479177387814f * shf[0*3+ch]
                    - 0.4886025119029199f * sy * shf[1*3+ch]
                    + 0.4886025119029199f * sz * shf[2*3+ch]
                    - 0.4886025119029199f * sx * shf[3*3+ch]
                    + 1.0925484305920792f  * xy * shf[4*3+ch]
                    + (-1.0925484305920792f) * yz * shf[5*3+ch]
                    + 0.31539156525252005f * (2.f*zz - xx - yy) * shf[6*3+ch]
                    + (-1.0925484305920792f) * xz * shf[7*3+ch]
                    + 0.5462742152960396f  * (xx - yy) * shf[8*3+ch]
                    + (-0.5900435899266435f) * sy * (3.f*xx - yy) * shf[9*3+ch]
                    + 2.890611442640554f   * xy * sz * shf[10*3+ch]
                    + (-0.4570457994644658f) * sy * (4.f*zz - xx - yy) * shf[11*3+ch]
                    + 0.3731763325901154f  * sz * (2.f*zz - 3.f*xx - 3.f*yy) * shf[12*3+ch]
                    + (-0.4570457994644658f) * sx * (4.f*zz - xx - yy) * shf[13*3+ch]
                    + 1.445305721320277f   * sz * (xx - yy) * shf[14*3+ch]
                    + (-0.5900435899266435f) * sx * (xx - 3.f*yy) * shf[15*3+ch];
                col[ch] = fmaxf(res + 0.5f, 0.0f);
            }
            colR[lane] = col[0]; colG[lane] = col[1]; colB[lane] = col[2];
        }
        __syncthreads();

        int nb = min(64, M - base);
        for (int j = 0; j < nb; ++j) {
            int idx = (int)(keys[base + j] & 0xFFFFFFFFu);   // LDS broadcast
            float gx = gxA[idx], gy = gyA[idx];
            float A  = cAA[idx], B  = cBA[idx], C = cCA[idx], op = opA[idx];
            float dx = gx - px, dy = gy - py;
            float power = -0.5f * (A*dx*dx + C*dy*dy) - B*dx*dy;
            float alpha = fminf(0.99f, op * __expf(power));
            if (live && power <= 0.0f && alpha >= (1.0f/255.0f)) {
                float Tnew = T * (1.0f - alpha);
                if (Tnew < 1e-4f) {
                    live = false;           // exact: ae_j and all later ae are 0
                } else {
                    float w = T * alpha;
                    cr += w * colR[j]; cg += w * colG[j]; cb += w * colB[j];
                    Tfin *= (1.0f - alpha);
                    T = Tnew;
                }
            }
        }
        __syncthreads();
        if (__ballot(live) == 0ull) break;
    }

    int p = (int)py * W_IMG + (int)px;
    out[p]                 = cr + bg[0] * Tfin;
    out[H_IMG*W_IMG + p]   = cg + bg[1] * Tfin;
    out[2*H_IMG*W_IMG + p] = cb + bg[2] * Tfin;
}

extern "C" void kernel_launch(void* const* d_in, const int* in_sizes, int n_in,
                              void* d_out, int out_size, void* d_ws, size_t ws_size,
                              hipStream_t stream) {
    const float* means3D = (const float*)d_in[0];
    const float* opac    = (const float*)d_in[2];
    const float* shs     = (const float*)d_in[3];
    const float* scales  = (const float*)d_in[4];
    const float* rot     = (const float*)d_in[5];
    const float* vm      = (const float*)d_in[6];
    const float* pm      = (const float*)d_in[7];
    const float* campos  = (const float*)d_in[8];
    const float* bg      = (const float*)d_in[9];

    gauss_tile_kernel<<<N_TILES, 64, 0, stream>>>(
        means3D, opac, shs, scales, rot, vm, pm, campos, bg, (float*)d_out);
}

// Round 7
// 89.720 us; speedup vs baseline: 1.7197x; 1.1739x over previous
//
#include <hip/hip_runtime.h>
#include <stdint.h>

#define N_G   1024
#define H_IMG 128
#define W_IMG 128
#define TILE  8
#define TILES_X (W_IMG / TILE)            // 16
#define N_TILES (TILES_X * (H_IMG/TILE))  // 256
#define NT    256                          // threads per block (4 waves)
#define FXc   128.0f
#define FYc   128.0f

// One dispatch, zero inter-block communication (grid barriers cost ~40us each
// on multi-XCD CDNA — R5; extra dispatches ~13us each — R3/R4). Each block owns
// one 8x8 tile and redundantly recomputes per-gaussian data. R6 lesson: NO
// dynamically-indexed private arrays (they lower to scratch when the owning
// loop isn't unrolled; with 1 block/CU the spill latency is fully exposed) —
// all staging lives in LDS SoA instead.
__global__ __launch_bounds__(NT) void gauss_tile_kernel(
    const float* __restrict__ means3D, const float* __restrict__ opac,
    const float* __restrict__ shs,     const float* __restrict__ scales,
    const float* __restrict__ rot,     const float* __restrict__ vm,
    const float* __restrict__ pm,      const float* __restrict__ campos,
    const float* __restrict__ bg,
    float* __restrict__ out)           // color (3,H,W) then radii (N_G)
{
    __shared__ float gxA[N_G], gyA[N_G], cAA[N_G], cBA[N_G], cCA[N_G],
                     opA[N_G], rcA[N_G];
    __shared__ unsigned int dpA[N_G];
    __shared__ unsigned long long keys[N_G];
    __shared__ float colR[N_G], colG[N_G], colB[N_G];
    __shared__ int cnt;

    const int t   = threadIdx.x;
    const int bid = blockIdx.x;
    const int tx = bid & (TILES_X - 1), ty = bid / TILES_X;
    const float x0 = (float)(tx * TILE), x1 = x0 + (float)(TILE - 1);
    const float y0 = (float)(ty * TILE), y1 = y0 + (float)(TILE - 1);

    if (t == 0) cnt = 0;

    // ---------------- Phase 1: conic prep for ALL gaussians (4 per thread) ----------------
    for (int k = 0; k < N_G / NT; ++k) {
        const int n = k * NT + t;

        float mx = means3D[n*3+0], my = means3D[n*3+1], mz = means3D[n*3+2];

        float pv0   = mx*vm[0] + my*vm[4] + mz*vm[8]  + vm[12];
        float pv1   = mx*vm[1] + my*vm[5] + mz*vm[9]  + vm[13];
        float depth = mx*vm[2] + my*vm[6] + mz*vm[10] + vm[14];
        bool dvalid = depth > 0.2f;

        float ph0 = mx*pm[0] + my*pm[4] + mz*pm[8]  + pm[12];
        float ph1 = mx*pm[1] + my*pm[5] + mz*pm[9]  + pm[13];
        float ph3 = mx*pm[3] + my*pm[7] + mz*pm[11] + pm[15];
        float invw = 1.0f / (ph3 + 1e-7f);
        float pp0 = ph0 * invw, pp1 = ph1 * invw;

        float4 q = *(const float4*)(rot + n*4);
        float qn = sqrtf(q.x*q.x + q.y*q.y + q.z*q.z + q.w*q.w);
        float qr = q.x/qn, qx = q.y/qn, qy = q.z/qn, qz = q.w/qn;
        float R00 = 1.f - 2.f*(qy*qy + qz*qz), R01 = 2.f*(qx*qy - qr*qz), R02 = 2.f*(qx*qz + qr*qy);
        float R10 = 2.f*(qx*qy + qr*qz), R11 = 1.f - 2.f*(qx*qx + qz*qz), R12 = 2.f*(qy*qz - qr*qx);
        float R20 = 2.f*(qx*qz - qr*qy), R21 = 2.f*(qy*qz + qr*qx), R22 = 1.f - 2.f*(qx*qx + qy*qy);

        float s0 = scales[n*3+0], s1 = scales[n*3+1], s2 = scales[n*3+2];
        float M00=R00*s0, M01=R01*s1, M02=R02*s2;
        float M10=R10*s0, M11=R11*s1, M12=R12*s2;
        float M20=R20*s0, M21=R21*s1, M22=R22*s2;

        float S00 = M00*M00 + M01*M01 + M02*M02;
        float S01 = M00*M10 + M01*M11 + M02*M12;
        float S02 = M00*M20 + M01*M21 + M02*M22;
        float S11 = M10*M10 + M11*M11 + M12*M12;
        float S12 = M10*M20 + M11*M21 + M12*M22;
        float S22 = M20*M20 + M21*M21 + M22*M22;

        float tz   = dvalid ? depth : 1.0f;
        float txtz = fminf(fmaxf(pv0 / tz, -0.65f), 0.65f) * tz;
        float tytz = fminf(fmaxf(pv1 / tz, -0.65f), 0.65f) * tz;
        float J00 = FXc / tz, J02 = -FXc * txtz / (tz*tz);
        float J11 = FYc / tz, J12 = -FYc * tytz / (tz*tz);

        float T20k0 = J00*vm[0] + J02*vm[2];
        float T20k1 = J00*vm[4] + J02*vm[6];
        float T20k2 = J00*vm[8] + J02*vm[10];
        float T21k0 = J11*vm[1] + J12*vm[2];
        float T21k1 = J11*vm[5] + J12*vm[6];
        float T21k2 = J11*vm[9] + J12*vm[10];

        float U00 = T20k0*S00 + T20k1*S01 + T20k2*S02;
        float U01 = T20k0*S01 + T20k1*S11 + T20k2*S12;
        float U02 = T20k0*S02 + T20k1*S12 + T20k2*S22;
        float U10 = T21k0*S00 + T21k1*S01 + T21k2*S02;
        float U11 = T21k0*S01 + T21k1*S11 + T21k2*S12;
        float U12 = T21k0*S02 + T21k1*S12 + T21k2*S22;
        float cov00 = U00*T20k0 + U01*T20k1 + U02*T20k2;
        float cov01 = U00*T21k0 + U01*T21k1 + U02*T21k2;
        float cov11 = U10*T21k0 + U11*T21k1 + U12*T21k2;

        float a = cov00 + 0.3f, b = cov01, c = cov11 + 0.3f;
        float det = a*c - b*b;
        bool valid = dvalid && (det > 0.0f);
        float inv_det = (det > 0.0f) ? (1.0f / det) : 1.0f;

        float mid  = 0.5f * (a + c);
        float lam1 = mid + sqrtf(fmaxf(0.1f, mid*mid - det));
        if (bid == 0)
            out[3*H_IMG*W_IMG + n] = valid ? ceilf(3.0f * sqrtf(lam1)) : 0.0f;

        float op = opac[n];
        float op255 = op * 255.0f;
        float rc2 = (valid && op255 > 1.0f) ? (2.0f * logf(op255) * lam1 * 1.01f + 1.0f)
                                            : -1.0f;   // always fails the cull test

        gxA[n] = ((pp0 + 1.0f) * (float)W_IMG - 1.0f) * 0.5f;
        gyA[n] = ((pp1 + 1.0f) * (float)H_IMG - 1.0f) * 0.5f;
        cAA[n] = c * inv_det;
        cBA[n] = -b * inv_det;
        cCA[n] = a * inv_det;
        opA[n] = op;
        rcA[n] = rc2;
        dpA[n] = __float_as_uint(depth);   // valid => depth>0.2 => bit order = value order
    }
    __syncthreads();

    // ---------------- Phase 2: cull (slot order canonicalized by the sort) ----------------
    for (int k = 0; k < N_G / NT; ++k) {
        const int n = k * NT + t;
        float gx = gxA[n], gy = gyA[n];
        float cx = fminf(fmaxf(gx, x0), x1) - gx;
        float cy = fminf(fmaxf(gy, y0), y1) - gy;
        if (cx*cx + cy*cy <= rcA[n]) {
            int slot = atomicAdd(&cnt, 1);
            keys[slot] = ((unsigned long long)dpA[n] << 32) | (unsigned int)n;
        }
    }
    __syncthreads();
    const int M = cnt;

    // ---------------- Phase 3: bitonic sort survivors by (depth_bits, idx) ----------------
    // Unique keys => canonical total order == reference's stable depth argsort
    // restricted to this tile's survivors (exact).
    int P = 1; while (P < M) P <<= 1;
    for (int i = M + t; i < P; i += NT) keys[i] = ~0ull;
    __syncthreads();
    for (int k = 2; k <= P; k <<= 1) {
        for (int j = k >> 1; j > 0; j >>= 1) {
            for (int i = t; i < P; i += NT) {
                int l = i ^ j;
                if (l > i) {
                    unsigned long long ka = keys[i], kb = keys[l];
                    bool asc = ((i & k) == 0);
                    if ((ka > kb) == asc) { keys[i] = kb; keys[l] = ka; }
                }
            }
            __syncthreads();
        }
    }

    // ---------------- Phase 4a: SH color for every survivor (streamed, no staging array) ----------------
    const float cpx = campos[0], cpy = campos[1], cpz = campos[2];
    for (int s = t; s < M; s += NT) {
        int idx = (int)(keys[s] & 0xFFFFFFFFu);
        float mx = means3D[idx*3+0], my = means3D[idx*3+1], mz = means3D[idx*3+2];
        float dxm = mx - cpx, dym = my - cpy, dzm = mz - cpz;
        float dn = sqrtf(dxm*dxm + dym*dym + dzm*dzm);
        float sx = dxm/dn, sy = dym/dn, sz = dzm/dn;
        float xx = sx*sx, yy = sy*sy, zz = sz*sz;
        float xy = sx*sy, yz = sy*sz, xz = sx*sz;

        float bb[16];
        bb[0]  = 0.28209479177387814f;
        bb[1]  = -0.4886025119029199f * sy;
        bb[2]  =  0.4886025119029199f * sz;
        bb[3]  = -0.4886025119029199f * sx;
        bb[4]  =  1.0925484305920792f * xy;
        bb[5]  = -1.0925484305920792f * yz;
        bb[6]  =  0.31539156525252005f * (2.f*zz - xx - yy);
        bb[7]  = -1.0925484305920792f * xz;
        bb[8]  =  0.5462742152960396f * (xx - yy);
        bb[9]  = -0.5900435899266435f * sy * (3.f*xx - yy);
        bb[10] =  2.890611442640554f  * xy * sz;
        bb[11] = -0.4570457994644658f * sy * (4.f*zz - xx - yy);
        bb[12] =  0.3731763325901154f * sz * (2.f*zz - 3.f*xx - 3.f*yy);
        bb[13] = -0.4570457994644658f * sx * (4.f*zz - xx - yy);
        bb[14] =  1.445305721320277f  * sz * (xx - yy);
        bb[15] = -0.5900435899266435f * sx * (xx - 3.f*yy);

        float acc[3] = {0.f, 0.f, 0.f};
        const float4* sh4 = (const float4*)(shs + idx*48);
        #pragma unroll
        for (int u = 0; u < 12; ++u) {
            float4 v = sh4[u];
            int f = 4*u;
            acc[(f+0)%3] += bb[(f+0)/3] * v.x;
            acc[(f+1)%3] += bb[(f+1)/3] * v.y;
            acc[(f+2)%3] += bb[(f+2)/3] * v.z;
            acc[(f+3)%3] += bb[(f+3)/3] * v.w;
        }
        colR[s] = fmaxf(acc[0] + 0.5f, 0.f);
        colG[s] = fmaxf(acc[1] + 0.5f, 0.f);
        colB[s] = fmaxf(acc[2] + 0.5f, 0.f);
    }
    __syncthreads();

    // ---------------- Phase 4b: blend (wave 0 only; 64 px tile; no further barriers) ----------------
    if (t < 64) {
        const float px = x0 + (float)(t & (TILE - 1));
        const float py = y0 + (float)(t / TILE);
        float T = 1.0f, Tfin = 1.0f, cr = 0.f, cg = 0.f, cb = 0.f;
        bool live = true;

        for (int j = 0; j < M; ++j) {
            int idx = (int)(keys[j] & 0xFFFFFFFFu);   // LDS broadcast
            float gx = gxA[idx], gy = gyA[idx];
            float A  = cAA[idx], B  = cBA[idx], C = cCA[idx], op = opA[idx];
            float dx = gx - px, dy = gy - py;
            float power = -0.5f * (A*dx*dx + C*dy*dy) - B*dx*dy;
            float alpha = fminf(0.99f, op * __expf(power));
            if (live && power <= 0.0f && alpha >= (1.0f/255.0f)) {
                float Tnew = T * (1.0f - alpha);
                if (Tnew < 1e-4f) {
                    live = false;           // exact: ae_j and all later ae are 0
                } else {
                    float w = T * alpha;
                    cr += w * colR[j]; cg += w * colG[j]; cb += w * colB[j];
                    Tfin *= (1.0f - alpha);
                    T = Tnew;
                }
            }
            if (__ballot(live) == 0ull) break;
        }

        int p = (int)py * W_IMG + (int)px;
        out[p]                 = cr + bg[0] * Tfin;
        out[H_IMG*W_IMG + p]   = cg + bg[1] * Tfin;
        out[2*H_IMG*W_IMG + p] = cb + bg[2] * Tfin;
    }
}

extern "C" void kernel_launch(void* const* d_in, const int* in_sizes, int n_in,
                              void* d_out, int out_size, void* d_ws, size_t ws_size,
                              hipStream_t stream) {
    const float* means3D = (const float*)d_in[0];
    const float* opac    = (const float*)d_in[2];
    const float* shs     = (const float*)d_in[3];
    const float* scales  = (const float*)d_in[4];
    const float* rot     = (const float*)d_in[5];
    const float* vm      = (const float*)d_in[6];
    const float* pm      = (const float*)d_in[7];
    const float* campos  = (const float*)d_in[8];
    const float* bg      = (const float*)d_in[9];

    gauss_tile_kernel<<<N_TILES, NT, 0, stream>>>(
        means3D, opac, shs, scales, rot, vm, pm, campos, bg, (float*)d_out);
}

// Round 8
// 88.357 us; speedup vs baseline: 1.7462x; 1.0154x over previous
//
#include <hip/hip_runtime.h>
#include <stdint.h>

#define N_G   1024
#define H_IMG 128
#define W_IMG 128
#define TILE  8
#define TILES_X (W_IMG / TILE)            // 16
#define N_TILES (TILES_X * (H_IMG/TILE))  // 256
#define NT    256                          // threads per block (4 waves)
#define CHUNK 256                          // sorted records staged per blend pass
#define FXc   128.0f
#define FYc   128.0f

// One dispatch, zero inter-block communication (grid barriers ~40us each on
// multi-XCD CDNA — R5; extra dispatches ~13us each — R3/R4). Each block owns
// one 8x8 tile, redundantly recomputing per-gaussian data.
// R6 lesson: no dynamically-indexed private arrays (scratch spill).
// R7 lesson: blend must read SEQUENTIAL pre-gathered LDS (the keys[j]->SoA[idx]
// indirection is a ~250-cyc dependent chain per record) and the bitonic sort's
// ~36 barriers are replaced by a barrier-free broadcast rank sort.
__global__ __launch_bounds__(NT) void gauss_tile_kernel(
    const float* __restrict__ means3D, const float* __restrict__ opac,
    const float* __restrict__ shs,     const float* __restrict__ scales,
    const float* __restrict__ rot,     const float* __restrict__ vm,
    const float* __restrict__ pm,      const float* __restrict__ campos,
    const float* __restrict__ bg,
    float* __restrict__ out)           // color (3,H,W) then radii (N_G)
{
    __shared__ float gxA[N_G], gyA[N_G], cAA[N_G], cBA[N_G], cCA[N_G], opA[N_G]; // 24 KB
    __shared__ unsigned long long svKeys[N_G];   // 8 KB  (survivors, arbitrary order)
    __shared__ int   ranks[N_G];                 // 4 KB
    __shared__ float srec[CHUNK * 12];           // 12 KB sorted AoS records
    __shared__ int   cnt, allDead;

    const int t   = threadIdx.x;
    const int bid = blockIdx.x;
    const int tx = bid & (TILES_X - 1), ty = bid / TILES_X;
    const float x0 = (float)(tx * TILE), x1 = x0 + (float)(TILE - 1);
    const float y0 = (float)(ty * TILE), y1 = y0 + (float)(TILE - 1);

    if (t == 0) { cnt = 0; allDead = 0; }
    __syncthreads();

    // ---------- Phase 1+2: prep all gaussians (4/thread, unrolled) + inline cull ----------
    #pragma unroll
    for (int k = 0; k < N_G / NT; ++k) {
        const int n = k * NT + t;

        float mx = means3D[n*3+0], my = means3D[n*3+1], mz = means3D[n*3+2];

        float pv0   = mx*vm[0] + my*vm[4] + mz*vm[8]  + vm[12];
        float pv1   = mx*vm[1] + my*vm[5] + mz*vm[9]  + vm[13];
        float depth = mx*vm[2] + my*vm[6] + mz*vm[10] + vm[14];
        bool dvalid = depth > 0.2f;

        float ph0 = mx*pm[0] + my*pm[4] + mz*pm[8]  + pm[12];
        float ph1 = mx*pm[1] + my*pm[5] + mz*pm[9]  + pm[13];
        float ph3 = mx*pm[3] + my*pm[7] + mz*pm[11] + pm[15];
        float invw = 1.0f / (ph3 + 1e-7f);
        float pp0 = ph0 * invw, pp1 = ph1 * invw;

        float4 q = *(const float4*)(rot + n*4);
        float qn = sqrtf(q.x*q.x + q.y*q.y + q.z*q.z + q.w*q.w);
        float qr = q.x/qn, qx = q.y/qn, qy = q.z/qn, qz = q.w/qn;
        float R00 = 1.f - 2.f*(qy*qy + qz*qz), R01 = 2.f*(qx*qy - qr*qz), R02 = 2.f*(qx*qz + qr*qy);
        float R10 = 2.f*(qx*qy + qr*qz), R11 = 1.f - 2.f*(qx*qx + qz*qz), R12 = 2.f*(qy*qz - qr*qx);
        float R20 = 2.f*(qx*qz - qr*qy), R21 = 2.f*(qy*qz + qr*qx), R22 = 1.f - 2.f*(qx*qx + qy*qy);

        float s0 = scales[n*3+0], s1 = scales[n*3+1], s2 = scales[n*3+2];
        float M00=R00*s0, M01=R01*s1, M02=R02*s2;
        float M10=R10*s0, M11=R11*s1, M12=R12*s2;
        float M20=R20*s0, M21=R21*s1, M22=R22*s2;

        float S00 = M00*M00 + M01*M01 + M02*M02;
        float S01 = M00*M10 + M01*M11 + M02*M12;
        float S02 = M00*M20 + M01*M21 + M02*M22;
        float S11 = M10*M10 + M11*M11 + M12*M12;
        float S12 = M10*M20 + M11*M21 + M12*M22;
        float S22 = M20*M20 + M21*M21 + M22*M22;

        float tz   = dvalid ? depth : 1.0f;
        float txtz = fminf(fmaxf(pv0 / tz, -0.65f), 0.65f) * tz;
        float tytz = fminf(fmaxf(pv1 / tz, -0.65f), 0.65f) * tz;
        float J00 = FXc / tz, J02 = -FXc * txtz / (tz*tz);
        float J11 = FYc / tz, J12 = -FYc * tytz / (tz*tz);

        float T20k0 = J00*vm[0] + J02*vm[2];
        float T20k1 = J00*vm[4] + J02*vm[6];
        float T20k2 = J00*vm[8] + J02*vm[10];
        float T21k0 = J11*vm[1] + J12*vm[2];
        float T21k1 = J11*vm[5] + J12*vm[6];
        float T21k2 = J11*vm[9] + J12*vm[10];

        float U00 = T20k0*S00 + T20k1*S01 + T20k2*S02;
        float U01 = T20k0*S01 + T20k1*S11 + T20k2*S12;
        float U02 = T20k0*S02 + T20k1*S12 + T20k2*S22;
        float U10 = T21k0*S00 + T21k1*S01 + T21k2*S02;
        float U11 = T21k0*S01 + T21k1*S11 + T21k2*S12;
        float U12 = T21k0*S02 + T21k1*S12 + T21k2*S22;
        float cov00 = U00*T20k0 + U01*T20k1 + U02*T20k2;
        float cov01 = U00*T21k0 + U01*T21k1 + U02*T21k2;
        float cov11 = U10*T21k0 + U11*T21k1 + U12*T21k2;

        float a = cov00 + 0.3f, b = cov01, c = cov11 + 0.3f;
        float det = a*c - b*b;
        bool valid = dvalid && (det > 0.0f);
        float inv_det = (det > 0.0f) ? (1.0f / det) : 1.0f;

        float mid  = 0.5f * (a + c);
        float lam1 = mid + sqrtf(fmaxf(0.1f, mid*mid - det));
        if (bid == 0)
            out[3*H_IMG*W_IMG + n] = valid ? ceilf(3.0f * sqrtf(lam1)) : 0.0f;

        float gx = ((pp0 + 1.0f) * (float)W_IMG - 1.0f) * 0.5f;
        float gy = ((pp1 + 1.0f) * (float)H_IMG - 1.0f) * 0.5f;
        float op = opac[n];

        gxA[n] = gx; gyA[n] = gy;
        cAA[n] = c * inv_det; cBA[n] = -b * inv_det; cCA[n] = a * inv_det;
        opA[n] = op;

        // conservative cull radius^2: alpha >= 1/255 needs |d|^2 <= 2 ln(255 op) lam1
        float op255 = op * 255.0f;
        float rc2 = (valid && op255 > 1.0f) ? (2.0f * logf(op255) * lam1 * 1.01f + 1.0f)
                                            : -1.0f;   // always fails cull

        float cx = fminf(fmaxf(gx, x0), x1) - gx;
        float cy = fminf(fmaxf(gy, y0), y1) - gy;
        if (cx*cx + cy*cy <= rc2) {
            int slot = atomicAdd(&cnt, 1);
            // valid => depth>0.2 => positive float => bit order = value order
            svKeys[slot] = ((unsigned long long)__float_as_uint(depth) << 32) | (unsigned int)n;
        }
    }
    __syncthreads();
    const int M = cnt;

    // ---------- Phase 3: barrier-free rank sort (broadcast scan; keys unique) ----------
    // rank == position in the reference's stable depth argsort restricted to
    // this tile's survivors — exact.
    for (int s = t; s < M; s += NT) {
        unsigned long long key = svKeys[s];
        int r = 0;
        for (int j = 0; j < M; ++j)           // same j across threads -> LDS broadcast
            r += (svKeys[j] < key) ? 1 : 0;
        ranks[s] = r;
    }
    __syncthreads();

    // ---------- Phase 4: chunked sorted scatter + sequential-LDS blend ----------
    const float cpx = campos[0], cpy = campos[1], cpz = campos[2];
    const float px = x0 + (float)(t & (TILE - 1));
    const float py = y0 + (float)((t >> 3) & (TILE - 1));   // valid for t<64
    float T = 1.0f, Tfin = 1.0f, cr = 0.f, cg = 0.f, cb = 0.f;
    bool live = true;

    for (int base = 0; base < M; base += CHUNK) {
        // scatter records with rank in [base, base+CHUNK) into srec, sorted
        for (int s = t; s < M; s += NT) {
            int r = ranks[s] - base;
            if (r >= 0 && r < CHUNK) {
                int idx = (int)(svKeys[s] & 0xFFFFFFFFu);

                // SH -> RGB for this survivor (constant-indexed, SROA-safe)
                float mx = means3D[idx*3+0], my = means3D[idx*3+1], mz = means3D[idx*3+2];
                float dxm = mx - cpx, dym = my - cpy, dzm = mz - cpz;
                float dn = sqrtf(dxm*dxm + dym*dym + dzm*dzm);
                float sx = dxm/dn, sy = dym/dn, sz = dzm/dn;
                float xx = sx*sx, yy = sy*sy, zz = sz*sz;
                float xy = sx*sy, yz = sy*sz, xz = sx*sz;
                float bb[16];
                bb[0]  = 0.28209479177387814f;
                bb[1]  = -0.4886025119029199f * sy;
                bb[2]  =  0.4886025119029199f * sz;
                bb[3]  = -0.4886025119029199f * sx;
                bb[4]  =  1.0925484305920792f * xy;
                bb[5]  = -1.0925484305920792f * yz;
                bb[6]  =  0.31539156525252005f * (2.f*zz - xx - yy);
                bb[7]  = -1.0925484305920792f * xz;
                bb[8]  =  0.5462742152960396f * (xx - yy);
                bb[9]  = -0.5900435899266435f * sy * (3.f*xx - yy);
                bb[10] =  2.890611442640554f  * xy * sz;
                bb[11] = -0.4570457994644658f * sy * (4.f*zz - xx - yy);
                bb[12] =  0.3731763325901154f * sz * (2.f*zz - 3.f*xx - 3.f*yy);
                bb[13] = -0.4570457994644658f * sx * (4.f*zz - xx - yy);
                bb[14] =  1.445305721320277f  * sz * (xx - yy);
                bb[15] = -0.5900435899266435f * sx * (xx - 3.f*yy);

                float acc0 = 0.f, acc1 = 0.f, acc2 = 0.f;
                const float4* sh4 = (const float4*)(shs + idx*48);
                #pragma unroll
                for (int u = 0; u < 12; ++u) {
                    float4 v = sh4[u];
                    const int f = 4*u;
                    // channel = flat%3, coeff = flat/3 — all constants post-unroll
                    if ((f+0)%3==0) acc0 += bb[(f+0)/3]*v.x; else if ((f+0)%3==1) acc1 += bb[(f+0)/3]*v.x; else acc2 += bb[(f+0)/3]*v.x;
                    if ((f+1)%3==0) acc0 += bb[(f+1)/3]*v.y; else if ((f+1)%3==1) acc1 += bb[(f+1)/3]*v.y; else acc2 += bb[(f+1)/3]*v.y;
                    if ((f+2)%3==0) acc0 += bb[(f+2)/3]*v.z; else if ((f+2)%3==1) acc1 += bb[(f+2)/3]*v.z; else acc2 += bb[(f+2)/3]*v.z;
                    if ((f+3)%3==0) acc0 += bb[(f+3)/3]*v.w; else if ((f+3)%3==1) acc1 += bb[(f+3)/3]*v.w; else acc2 += bb[(f+3)/3]*v.w;
                }

                float* rp = srec + r * 12;
                rp[0] = gxA[idx]; rp[1] = gyA[idx]; rp[2] = cAA[idx]; rp[3] = cBA[idx];
                rp[4] = cCA[idx]; rp[5] = opA[idx];
                rp[6] = fmaxf(acc0 + 0.5f, 0.f);
                rp[7] = fmaxf(acc1 + 0.5f, 0.f);
                rp[8] = fmaxf(acc2 + 0.5f, 0.f);
            }
        }
        __syncthreads();

        // blend: wave 0, sequential LDS reads (affine addresses -> pipelined)
        if (t < 64) {
            int nb = min(CHUNK, M - base);
            for (int j = 0; j < nb; ++j) {
                const float* g = srec + j * 12;
                float4 g0 = *(const float4*)(g);      // gx gy A B
                float4 g1 = *(const float4*)(g + 4);  // C op r g
                float  b2 = g[8];                     // b
                float dx = g0.x - px, dy = g0.y - py;
                float power = -0.5f * (g0.z*dx*dx + g1.x*dy*dy) - g0.w*dx*dy;
                float alpha = fminf(0.99f, g1.y * __expf(power));
                if (live && power <= 0.0f && alpha >= (1.0f/255.0f)) {
                    float Tnew = T * (1.0f - alpha);
                    if (Tnew < 1e-4f) {
                        live = false;          // exact: ae_j and all later ae are 0
                    } else {
                        float w = T * alpha;
                        cr += w * g1.z; cg += w * g1.w; cb += w * b2;
                        Tfin *= (1.0f - alpha);
                        T = Tnew;
                    }
                }
                if (__ballot(live) == 0ull) break;
            }
            if (__ballot(live) == 0ull && t == 0) allDead = 1;
        }
        __syncthreads();
        if (allDead) break;                   // block-uniform after barrier
    }

    if (t < 64) {
        int p = (int)py * W_IMG + (int)px;
        out[p]                 = cr + bg[0] * Tfin;
        out[H_IMG*W_IMG + p]   = cg + bg[1] * Tfin;
        out[2*H_IMG*W_IMG + p] = cb + bg[2] * Tfin;
    }
}

extern "C" void kernel_launch(void* const* d_in, const int* in_sizes, int n_in,
                              void* d_out, int out_size, void* d_ws, size_t ws_size,
                              hipStream_t stream) {
    const float* means3D = (const float*)d_in[0];
    const float* opac    = (const float*)d_in[2];
    const float* shs     = (const float*)d_in[3];
    const float* scales  = (const float*)d_in[4];
    const float* rot     = (const float*)d_in[5];
    const float* vm      = (const float*)d_in[6];
    const float* pm      = (const float*)d_in[7];
    const float* campos  = (const float*)d_in[8];
    const float* bg      = (const float*)d_in[9];

    gauss_tile_kernel<<<N_TILES, NT, 0, stream>>>(
        means3D, opac, shs, scales, rot, vm, pm, campos, bg, (float*)d_out);
}

// Round 9
// 83.994 us; speedup vs baseline: 1.8369x; 1.0519x over previous
//
#include <hip/hip_runtime.h>
#include <stdint.h>

#define N_G   1024
#define H_IMG 128
#define W_IMG 128
#define TILE  8
#define TILES_X (W_IMG / TILE)            // 16
#define N_TILES (TILES_X * (H_IMG/TILE))  // 256
#define NT    512                          // 8 waves/block -> 2 waves/SIMD (latency hiding)
#define CHUNK 256                          // sorted records staged per blend pass
#define FXc   128.0f
#define FYc   128.0f

// One dispatch, zero inter-block communication (grid barriers ~40us each on
// multi-XCD CDNA — R5; extra dispatches ~13us each — R3/R4). Each block owns
// one 8x8 tile, redundantly recomputing per-gaussian data.
// R6 lesson: no dynamically-indexed private arrays (scratch spill).
// R7 lesson: blend reads sequential pre-gathered LDS; rank sort not bitonic.
// R8 lesson: sort/blend were NOT the cost — prep is (1 wave/SIMD + precise
// div/sqrt chains). R9: NT=512 + v_rcp/v_rsq/v_log fast intrinsics.
__global__ __launch_bounds__(NT) void gauss_tile_kernel(
    const float* __restrict__ means3D, const float* __restrict__ opac,
    const float* __restrict__ shs,     const float* __restrict__ scales,
    const float* __restrict__ rot,     const float* __restrict__ vm,
    const float* __restrict__ pm,      const float* __restrict__ campos,
    const float* __restrict__ bg,
    float* __restrict__ out)           // color (3,H,W) then radii (N_G)
{
    __shared__ float gxA[N_G], gyA[N_G], cAA[N_G], cBA[N_G], cCA[N_G], opA[N_G]; // 24 KB
    __shared__ unsigned long long svKeys[N_G];   // 8 KB  (survivors, arbitrary order)
    __shared__ int   ranks[N_G];                 // 4 KB
    __shared__ float srec[CHUNK * 12];           // 12 KB sorted AoS records
    __shared__ int   cnt, allDead;

    const int t   = threadIdx.x;
    const int bid = blockIdx.x;
    const int tx = bid & (TILES_X - 1), ty = bid / TILES_X;
    const float x0 = (float)(tx * TILE), x1 = x0 + (float)(TILE - 1);
    const float y0 = (float)(ty * TILE), y1 = y0 + (float)(TILE - 1);

    if (t == 0) { cnt = 0; allDead = 0; }
    __syncthreads();

    // ---------- Phase 1+2: prep all gaussians (2/thread) + inline cull ----------
    #pragma unroll
    for (int k = 0; k < N_G / NT; ++k) {
        const int n = k * NT + t;

        float mx = means3D[n*3+0], my = means3D[n*3+1], mz = means3D[n*3+2];

        float pv0   = mx*vm[0] + my*vm[4] + mz*vm[8]  + vm[12];
        float pv1   = mx*vm[1] + my*vm[5] + mz*vm[9]  + vm[13];
        float depth = mx*vm[2] + my*vm[6] + mz*vm[10] + vm[14];
        bool dvalid = depth > 0.2f;

        float ph0 = mx*pm[0] + my*pm[4] + mz*pm[8]  + pm[12];
        float ph1 = mx*pm[1] + my*pm[5] + mz*pm[9]  + pm[13];
        float ph3 = mx*pm[3] + my*pm[7] + mz*pm[11] + pm[15];
        float invw = __builtin_amdgcn_rcpf(ph3 + 1e-7f);
        float pp0 = ph0 * invw, pp1 = ph1 * invw;

        float4 q = *(const float4*)(rot + n*4);
        float qinv = __builtin_amdgcn_rsqf(q.x*q.x + q.y*q.y + q.z*q.z + q.w*q.w);
        float qr = q.x*qinv, qx = q.y*qinv, qy = q.z*qinv, qz = q.w*qinv;
        float R00 = 1.f - 2.f*(qy*qy + qz*qz), R01 = 2.f*(qx*qy - qr*qz), R02 = 2.f*(qx*qz + qr*qy);
        float R10 = 2.f*(qx*qy + qr*qz), R11 = 1.f - 2.f*(qx*qx + qz*qz), R12 = 2.f*(qy*qz - qr*qx);
        float R20 = 2.f*(qx*qz - qr*qy), R21 = 2.f*(qy*qz + qr*qx), R22 = 1.f - 2.f*(qx*qx + qy*qy);

        float s0 = scales[n*3+0], s1 = scales[n*3+1], s2 = scales[n*3+2];
        float M00=R00*s0, M01=R01*s1, M02=R02*s2;
        float M10=R10*s0, M11=R11*s1, M12=R12*s2;
        float M20=R20*s0, M21=R21*s1, M22=R22*s2;

        float S00 = M00*M00 + M01*M01 + M02*M02;
        float S01 = M00*M10 + M01*M11 + M02*M12;
        float S02 = M00*M20 + M01*M21 + M02*M22;
        float S11 = M10*M10 + M11*M11 + M12*M12;
        float S12 = M10*M20 + M11*M21 + M12*M22;
        float S22 = M20*M20 + M21*M21 + M22*M22;

        float tz   = dvalid ? depth : 1.0f;
        float itz  = __builtin_amdgcn_rcpf(tz);
        float txtz = fminf(fmaxf(pv0 * itz, -0.65f), 0.65f) * tz;
        float tytz = fminf(fmaxf(pv1 * itz, -0.65f), 0.65f) * tz;
        float J00 = FXc * itz, J02 = -FXc * txtz * itz * itz;
        float J11 = FYc * itz, J12 = -FYc * tytz * itz * itz;

        float T20k0 = J00*vm[0] + J02*vm[2];
        float T20k1 = J00*vm[4] + J02*vm[6];
        float T20k2 = J00*vm[8] + J02*vm[10];
        float T21k0 = J11*vm[1] + J12*vm[2];
        float T21k1 = J11*vm[5] + J12*vm[6];
        float T21k2 = J11*vm[9] + J12*vm[10];

        float U00 = T20k0*S00 + T20k1*S01 + T20k2*S02;
        float U01 = T20k0*S01 + T20k1*S11 + T20k2*S12;
        float U02 = T20k0*S02 + T20k1*S12 + T20k2*S22;
        float U10 = T21k0*S00 + T21k1*S01 + T21k2*S02;
        float U11 = T21k0*S01 + T21k1*S11 + T21k2*S12;
        float U12 = T21k0*S02 + T21k1*S12 + T21k2*S22;
        float cov00 = U00*T20k0 + U01*T20k1 + U02*T20k2;
        float cov01 = U00*T21k0 + U01*T21k1 + U02*T21k2;
        float cov11 = U10*T21k0 + U11*T21k1 + U12*T21k2;

        float a = cov00 + 0.3f, b = cov01, c = cov11 + 0.3f;
        float det = a*c - b*b;
        bool valid = dvalid && (det > 0.0f);
        float inv_det = (det > 0.0f) ? __builtin_amdgcn_rcpf(det) : 1.0f;

        float mid  = 0.5f * (a + c);
        // precise sqrtf: feeds the integer-compared radii output (ceil boundary)
        float lam1 = mid + sqrtf(fmaxf(0.1f, mid*mid - det));
        if (bid == 0)
            out[3*H_IMG*W_IMG + n] = valid ? ceilf(3.0f * sqrtf(lam1)) : 0.0f;

        float gx = ((pp0 + 1.0f) * (float)W_IMG - 1.0f) * 0.5f;
        float gy = ((pp1 + 1.0f) * (float)H_IMG - 1.0f) * 0.5f;
        float op = opac[n];

        gxA[n] = gx; gyA[n] = gy;
        cAA[n] = c * inv_det; cBA[n] = -b * inv_det; cCA[n] = a * inv_det;
        opA[n] = op;

        // conservative cull radius^2: alpha >= 1/255 needs |d|^2 <= 2 ln(255 op) lam1.
        // fast __logf is safe: the 1.01x + 1 margin dwarfs its ulp error.
        float op255 = op * 255.0f;
        float rc2 = (valid && op255 > 1.0f) ? (2.0f * __logf(op255) * lam1 * 1.01f + 1.0f)
                                            : -1.0f;   // always fails cull

        float cx = fminf(fmaxf(gx, x0), x1) - gx;
        float cy = fminf(fmaxf(gy, y0), y1) - gy;
        if (cx*cx + cy*cy <= rc2) {
            int slot = atomicAdd(&cnt, 1);
            // valid => depth>0.2 => positive float => bit order = value order
            svKeys[slot] = ((unsigned long long)__float_as_uint(depth) << 32) | (unsigned int)n;
        }
    }
    __syncthreads();
    const int M = cnt;

    // ---------- Phase 3: barrier-free rank sort (broadcast scan; keys unique) ----------
    for (int s = t; s < M; s += NT) {
        unsigned long long key = svKeys[s];
        int r = 0;
        for (int j = 0; j < M; ++j)           // same j across threads -> LDS broadcast
            r += (svKeys[j] < key) ? 1 : 0;
        ranks[s] = r;
    }
    __syncthreads();

    // ---------- Phase 4: chunked sorted scatter + sequential-LDS blend ----------
    const float cpx = campos[0], cpy = campos[1], cpz = campos[2];
    const float px = x0 + (float)(t & (TILE - 1));
    const float py = y0 + (float)((t >> 3) & (TILE - 1));   // valid for t<64
    float T = 1.0f, Tfin = 1.0f, cr = 0.f, cg = 0.f, cb = 0.f;
    bool live = true;

    for (int base = 0; base < M; base += CHUNK) {
        // scatter records with rank in [base, base+CHUNK) into srec, sorted
        for (int s = t; s < M; s += NT) {
            int r = ranks[s] - base;
            if (r >= 0 && r < CHUNK) {
                int idx = (int)(svKeys[s] & 0xFFFFFFFFu);

                // SH -> RGB (constant-indexed, SROA-safe)
                float mx = means3D[idx*3+0], my = means3D[idx*3+1], mz = means3D[idx*3+2];
                float dxm = mx - cpx, dym = my - cpy, dzm = mz - cpz;
                float rinv = __builtin_amdgcn_rsqf(dxm*dxm + dym*dym + dzm*dzm);
                float sx = dxm*rinv, sy = dym*rinv, sz = dzm*rinv;
                float xx = sx*sx, yy = sy*sy, zz = sz*sz;
                float xy = sx*sy, yz = sy*sz, xz = sx*sz;
                float bb[16];
                bb[0]  = 0.28209479177387814f;
                bb[1]  = -0.4886025119029199f * sy;
                bb[2]  =  0.4886025119029199f * sz;
                bb[3]  = -0.4886025119029199f * sx;
                bb[4]  =  1.0925484305920792f * xy;
                bb[5]  = -1.0925484305920792f * yz;
                bb[6]  =  0.31539156525252005f * (2.f*zz - xx - yy);
                bb[7]  = -1.0925484305920792f * xz;
                bb[8]  =  0.5462742152960396f * (xx - yy);
                bb[9]  = -0.5900435899266435f * sy * (3.f*xx - yy);
                bb[10] =  2.890611442640554f  * xy * sz;
                bb[11] = -0.4570457994644658f * sy * (4.f*zz - xx - yy);
                bb[12] =  0.3731763325901154f * sz * (2.f*zz - 3.f*xx - 3.f*yy);
                bb[13] = -0.4570457994644658f * sx * (4.f*zz - xx - yy);
                bb[14] =  1.445305721320277f  * sz * (xx - yy);
                bb[15] = -0.5900435899266435f * sx * (xx - 3.f*yy);

                float acc0 = 0.f, acc1 = 0.f, acc2 = 0.f;
                const float4* sh4 = (const float4*)(shs + idx*48);
                #pragma unroll
                for (int u = 0; u < 12; ++u) {
                    float4 v = sh4[u];
                    const int f = 4*u;
                    if ((f+0)%3==0) acc0 += bb[(f+0)/3]*v.x; else if ((f+0)%3==1) acc1 += bb[(f+0)/3]*v.x; else acc2 += bb[(f+0)/3]*v.x;
                    if ((f+1)%3==0) acc0 += bb[(f+1)/3]*v.y; else if ((f+1)%3==1) acc1 += bb[(f+1)/3]*v.y; else acc2 += bb[(f+1)/3]*v.y;
                    if ((f+2)%3==0) acc0 += bb[(f+2)/3]*v.z; else if ((f+2)%3==1) acc1 += bb[(f+2)/3]*v.z; else acc2 += bb[(f+2)/3]*v.z;
                    if ((f+3)%3==0) acc0 += bb[(f+3)/3]*v.w; else if ((f+3)%3==1) acc1 += bb[(f+3)/3]*v.w; else acc2 += bb[(f+3)/3]*v.w;
                }

                float* rp = srec + r * 12;
                rp[0] = gxA[idx]; rp[1] = gyA[idx]; rp[2] = cAA[idx]; rp[3] = cBA[idx];
                rp[4] = cCA[idx]; rp[5] = opA[idx];
                rp[6] = fmaxf(acc0 + 0.5f, 0.f);
                rp[7] = fmaxf(acc1 + 0.5f, 0.f);
                rp[8] = fmaxf(acc2 + 0.5f, 0.f);
            }
        }
        __syncthreads();

        // blend: wave 0, sequential LDS reads (affine addresses -> pipelined)
        if (t < 64) {
            int nb = min(CHUNK, M - base);
            for (int j = 0; j < nb; ++j) {
                const float* g = srec + j * 12;
                float4 g0 = *(const float4*)(g);      // gx gy A B
                float4 g1 = *(const float4*)(g + 4);  // C op r g
                float  b2 = g[8];                     // b
                float dx = g0.x - px, dy = g0.y - py;
                float power = -0.5f * (g0.z*dx*dx + g1.x*dy*dy) - g0.w*dx*dy;
                float alpha = fminf(0.99f, g1.y * __expf(power));
                if (live && power <= 0.0f && alpha >= (1.0f/255.0f)) {
                    float Tnew = T * (1.0f - alpha);
                    if (Tnew < 1e-4f) {
                        live = false;          // exact: ae_j and all later ae are 0
                    } else {
                        float w = T * alpha;
                        cr += w * g1.z; cg += w * g1.w; cb += w * b2;
                        Tfin *= (1.0f - alpha);
                        T = Tnew;
                    }
                }
                if (__ballot(live) == 0ull) break;
            }
            if (__ballot(live) == 0ull && t == 0) allDead = 1;
        }
        __syncthreads();
        if (allDead) break;                   // block-uniform after barrier
    }

    if (t < 64) {
        int p = (int)py * W_IMG + (int)px;
        out[p]                 = cr + bg[0] * Tfin;
        out[H_IMG*W_IMG + p]   = cg + bg[1] * Tfin;
        out[2*H_IMG*W_IMG + p] = cb + bg[2] * Tfin;
    }
}

extern "C" void kernel_launch(void* const* d_in, const int* in_sizes, int n_in,
                              void* d_out, int out_size, void* d_ws, size_t ws_size,
                              hipStream_t stream) {
    const float* means3D = (const float*)d_in[0];
    const float* opac    = (const float*)d_in[2];
    const float* shs     = (const float*)d_in[3];
    const float* scales  = (const float*)d_in[4];
    const float* rot     = (const float*)d_in[5];
    const float* vm      = (const float*)d_in[6];
    const float* pm      = (const float*)d_in[7];
    const float* campos  = (const float*)d_in[8];
    const float* bg      = (const float*)d_in[9];

    gauss_tile_kernel<<<N_TILES, NT, 0, stream>>>(
        means3D, opac, shs, scales, rot, vm, pm, campos, bg, (float*)d_out);
}